// Round 7
// baseline (14.892 us; speedup 1.0000x reference)
//
#include <hip/hip_runtime.h>

namespace {

constexpr int B_ = 4, C_ = 64, H_ = 96, W_ = 192, S_ = 12;
constexpr int HW = H_ * W_;
constexpr float TEMP_OVER_C = 7.0f / 64.0f;   // TEMPERATURE / C
constexpr int OUT_HALF = B_ * 4 * H_ * W_;    // ndisp_out first, then disp_out
constexpr int WBLK = 48;                      // w-cols per tile
constexpr int SCOLS = 96;                     // staged right cols (48 + 48 halo)
constexpr int LSTR = 68;                      // stride: 68%32=4 -> b128 bank-conflict-free

// k in 0..2 samples, 16-channel chunk at C0 against left regs LR
#define GATHER_CHUNK(LR, C0)                                              \
  {                                                                       \
    _Pragma("unroll")                                                     \
    for (int k = 0; k < 3; ++k) {                                         \
      const float* rr = rlds + jb[k] + (C0);                              \
      const float4 r0 = *reinterpret_cast<const float4*>(rr);             \
      const float4 r1 = *reinterpret_cast<const float4*>(rr + 4);         \
      const float4 r2 = *reinterpret_cast<const float4*>(rr + 8);         \
      const float4 r3 = *reinterpret_cast<const float4*>(rr + 12);        \
      float a = st[k];                                                    \
      a = fmaf(LR[0],  r0.x, a);  a = fmaf(LR[1],  r0.y, a);              \
      a = fmaf(LR[2],  r0.z, a);  a = fmaf(LR[3],  r0.w, a);              \
      a = fmaf(LR[4],  r1.x, a);  a = fmaf(LR[5],  r1.y, a);              \
      a = fmaf(LR[6],  r1.z, a);  a = fmaf(LR[7],  r1.w, a);              \
      a = fmaf(LR[8],  r2.x, a);  a = fmaf(LR[9],  r2.y, a);              \
      a = fmaf(LR[10], r2.z, a);  a = fmaf(LR[11], r2.w, a);              \
      a = fmaf(LR[12], r3.x, a);  a = fmaf(LR[13], r3.y, a);              \
      a = fmaf(LR[14], r3.z, a);  a = fmaf(LR[15], r3.w, a);              \
      st[k] = a;                                                          \
    }                                                                     \
  }

__global__ __launch_bounds__(192, 5) void fused_eval(
    const float* __restrict__ left, const float* __restrict__ right,
    const float* __restrict__ disp, const float* __restrict__ ndisp,
    float* __restrict__ out)
{
  __shared__ float rlds[SCOLS * LSTR];   // 26112 B -> 6 blocks/CU

  // 1536 tiles = 8 XCDs x (48 rows x 4 chunks). Round-robin wgid%8 -> XCD:
  // all chunks of a row (and its 48-row band) share one XCD's L2 for halo reuse.
  const int xcd  = blockIdx.x & 7;
  const int slot = blockIdx.x >> 3;      // 0..191
  const int bh   = xcd * 48 + (slot >> 2);
  const int q    = slot & 3;             // row chunk 0..3
  const int b = bh / H_;
  const int h = bh - b * H_;
  const int w0 = q * WBLK;
  const int s0g = q ? (WBLK * q - 48) : 0;   // staged cols [s0g, s0g+96)

  const int t = threadIdx.x;             // 0..191
  const int l = t & 63;
  const int v = t >> 6;                  // wave 0..2
  const int wl = v * 16 + (l & 15);      // 0..47
  const int sg = (l >> 4) & 3;           // interval 0..3 (this thread's samples 3sg..3sg+2)
  const int w  = w0 + wl;

  // ---- staging reads first (they gate the barrier); 2x16 chans to cap VGPR ----
  const float* rrow = right + (size_t)b * C_ * HW + (size_t)h * W_ + s0g;
  const int ct = (t < 96) ? t : (t - 96);    // staged col 0..95
  const int cb = (t < 96) ? 0 : 32;          // channel base 0 / 32
  const float* src = rrow + (size_t)cb * HW + ct;
  float va[16], vb[16];
  #pragma unroll
  for (int j = 0; j < 16; ++j) va[j] = src[(size_t)j * HW];
  #pragma unroll
  for (int j = 0; j < 16; ++j) vb[j] = src[(size_t)(16 + j) * HW];

  // ---- sample setup (disp for idx) fills the staging latency shadow ----
  const size_t dbase = ((size_t)(b * S_ + 3 * sg) * H_ + h) * W_ + w;
  float dsp[3]; int jb[3];
  #pragma unroll
  for (int k = 0; k < 3; ++k) {
    dsp[k] = disp[dbase + (size_t)k * HW];
    // reference: clip(w - d, 0, W-1) in f32, then int32 truncation
    const float ry = fminf(fmaxf((float)w - dsp[k], 0.0f), (float)(W_ - 1));
    jb[k] = ((int)ry - s0g) * LSTR;
  }

  // left chunk 0: latency hides under LDS writes + barrier
  const float* lcol = left + (size_t)b * C_ * HW + (size_t)h * W_ + w;
  float la[16], lb[16];
  #pragma unroll
  for (int c = 0; c < 16; ++c) la[c] = lcol[(size_t)c * HW];

  // ---- LDS writes (transposed [col][chan], b128, conflict-free) ----
  {
    float* dst = &rlds[ct * LSTR + cb];
    #pragma unroll
    for (int j = 0; j < 4; ++j)
      *reinterpret_cast<float4*>(dst + 4 * j) =
          make_float4(va[4*j], va[4*j+1], va[4*j+2], va[4*j+3]);
    #pragma unroll
    for (int j = 0; j < 4; ++j)
      *reinterpret_cast<float4*>(dst + 16 + 4 * j) =
          make_float4(vb[4*j], vb[4*j+1], vb[4*j+2], vb[4*j+3]);
  }

  __syncthreads();

  // ndisp only needed in epilogue: issue now, hides under gather
  float nds[3];
  #pragma unroll
  for (int k = 0; k < 3; ++k) nds[k] = ndisp[dbase + (size_t)k * HW];

  // ---- gather: 3 samples x 64 chan, b128 LDS + pipelined left chunks ----
  float st[3] = {0.f, 0.f, 0.f};
  #pragma unroll
  for (int c = 0; c < 16; ++c) lb[c] = lcol[(size_t)(16 + c) * HW];
  GATHER_CHUNK(la, 0)
  #pragma unroll
  for (int c = 0; c < 16; ++c) la[c] = lcol[(size_t)(32 + c) * HW];
  GATHER_CHUNK(lb, 16)
  #pragma unroll
  for (int c = 0; c < 16; ++c) lb[c] = lcol[(size_t)(48 + c) * HW];
  GATHER_CHUNK(la, 32)
  GATHER_CHUNK(lb, 48)

  // ---- epilogue: this thread's one interval, fully static ----
  const float a0 = st[0] * TEMP_OVER_C;
  const float a1 = st[1] * TEMP_OVER_C;
  const float a2 = st[2] * TEMP_OVER_C;
  const float m  = fmaxf(a0, fmaxf(a1, a2));
  const float e0 = __expf(a0 - m);
  const float e1 = __expf(a1 - m);
  const float e2 = __expf(a2 - m);
  const float inv = 1.0f / (e0 + e1 + e2);
  const size_t o = ((size_t)(b * 4 + sg) * H_ + h) * W_ + w;
  out[o]            = (nds[0] * e0 + nds[1] * e1 + nds[2] * e2) * inv;
  out[OUT_HALF + o] = (dsp[0] * e0 + dsp[1] * e1 + dsp[2] * e2) * inv;
}

} // namespace

extern "C" void kernel_launch(void* const* d_in, const int* in_sizes, int n_in,
                              void* d_out, int out_size, void* d_ws, size_t ws_size,
                              hipStream_t stream) {
  const float* left  = (const float*)d_in[0];
  const float* right = (const float*)d_in[1];
  const float* disp  = (const float*)d_in[2];
  const float* ndisp = (const float*)d_in[3];
  float* out = (float*)d_out;
  dim3 grid(8 * 48 * 4);   // 1536 tiles
  dim3 block(192);
  hipLaunchKernelGGL(fused_eval, grid, block, 0, stream, left, right, disp, ndisp, out);
}